// Round 1
// baseline (930.520 us; speedup 1.0000x reference)
//
#include <hip/hip_runtime.h>
#include <math.h>

#define BB 4
#define CC 64
#define HH 112
#define WW 112
#define MD 20
#define KD 41            // 2*MD+1
#define NG 8             // dx groups per pixel row
#define SCALE 10000.0f   // 1/TEMP
#define NPIX (BB*HH*WW)  // 50176
#define PLANE (HH*WW)    // 12544
#define BROW 152         // staged row width: WW + 2*MD

// Kernel 1: per-pixel inverse L2 norm over channels for both inputs.
__global__ __launch_bounds__(128) void norm_kernel(const float* __restrict__ in1,
                                                   const float* __restrict__ in2,
                                                   float* __restrict__ inv1,
                                                   float* __restrict__ inv2) {
    int bid = blockIdx.x;              // [0, 2*B*H)
    int which = bid / (BB*HH);
    int rem = bid % (BB*HH);
    int b = rem / HH, h = rem % HH;
    int t = threadIdx.x;
    if (t >= WW) return;
    const float* src = which ? in2 : in1;
    float s = 0.f;
    #pragma unroll
    for (int c = 0; c < CC; ++c) {
        float x = src[((b*CC + c)*HH + h)*WW + t];   // coalesced across t
        s += x*x;
    }
    float inv = 1.0f / fmaxf(sqrtf(s), 1e-12f);
    (which ? inv2 : inv1)[(b*HH + h)*WW + t] = inv;
}

// Kernel 2: block = (b, h, dx-group). Thread = pixel w. A in registers,
// B row staged (normalized, zero-padded) in LDS [c][j]. Online softmax
// per thread over this group's dx rows; partial state written to ws.
__global__ __launch_bounds__(128) void corr_kernel(const float* __restrict__ in1,
                                                   const float* __restrict__ in2,
                                                   const float* __restrict__ inv1,
                                                   const float* __restrict__ inv2,
                                                   float* __restrict__ part) {
    __shared__ float ldsB[CC*BROW];    // 38912 B
    int bid = blockIdx.x;
    int g = bid & (NG-1);
    int rest = bid >> 3;
    int h = rest % HH;
    int b = rest / HH;
    int t = threadIdx.x;
    int tt = t < WW ? t : (WW-1);      // clamp idle lanes (keep LDS reads in-bounds)

    // A fragment: normalized in1 channel vector for this pixel (64 VGPRs)
    float a[CC];
    float i1 = inv1[(b*HH + h)*WW + tt];
    #pragma unroll
    for (int c = 0; c < CC; ++c)
        a[c] = in1[((b*CC + c)*HH + h)*WW + tt] * i1;   // coalesced across t

    // online softmax state
    float m = -INFINITY, l = 0.f, sx = 0.f, sy = 0.f;

    int lo = (g*KD)/NG, hi = ((g+1)*KD)/NG;  // contiguous dx chunk
    for (int di = lo; di < hi; ++di) {
        int dx = di - MD;
        int row = h + dx;
        if (row >= 0 && row < HH) {          // block-uniform branch
            __syncthreads();                  // protect previous tile's readers
            for (int i = t; i < CC*BROW; i += 128) {
                int c = i / BROW, j = i % BROW;
                int w = j - MD;
                float v = 0.f;
                if (w >= 0 && w < WW)
                    v = in2[((b*CC + c)*HH + row)*WW + w] * inv2[(b*HH + row)*WW + w];
                ldsB[i] = v;
            }
            __syncthreads();
            for (int dyi = 0; dyi < KD; ++dyi) {
                // dot over 64 channels; lanes stride 4B in LDS -> conflict-free
                float s0=0.f, s1=0.f, s2=0.f, s3=0.f;
                const float* bp = &ldsB[tt + dyi];
                #pragma unroll
                for (int c = 0; c < CC; c += 4) {
                    s0 += a[c+0]*bp[(c+0)*BROW];
                    s1 += a[c+1]*bp[(c+1)*BROW];
                    s2 += a[c+2]*bp[(c+2)*BROW];
                    s3 += a[c+3]*bp[(c+3)*BROW];
                }
                float s = (s0+s1)+(s2+s3);
                // weight < e^-30 if s <= m-0.003: negligible vs threshold 0.4
                if (s > m - 3.0e-3f) {
                    float mn = fmaxf(m, s);
                    float sc = __expf((m - mn)*SCALE);
                    float es = __expf((s - mn)*SCALE);
                    l  = l*sc + es;
                    sy = sy*sc + es*(float)(dyi - MD);
                    sx = sx*sc + es*(float)dx;
                    m = mn;
                }
            }
        } else {
            // out-of-range dx row: all 41 dy give sim == 0 exactly
            float mn = fmaxf(m, 0.f);
            float sc = __expf((m - mn)*SCALE);
            float e0 = __expf((0.f - mn)*SCALE);
            l  = l*sc + 41.f*e0;
            sy = sy*sc;                       // sum(dy) over -20..20 == 0
            sx = sx*sc + (float)dx*41.f*e0;
            m = mn;
        }
    }

    if (t < WW) {
        int pix = (b*HH + h)*WW + t;
        float* p = &part[(size_t)(g*NPIX + pix)*4];
        p[0] = m; p[1] = l; p[2] = sx; p[3] = sy;
    }
}

// Kernel 3: merge the NG partial softmax states per pixel, emit flow.
__global__ __launch_bounds__(256) void merge_kernel(const float* __restrict__ part,
                                                    float* __restrict__ out) {
    int idx = blockIdx.x*256 + threadIdx.x;
    if (idx >= NPIX) return;
    float M = -INFINITY;
    #pragma unroll
    for (int gg = 0; gg < NG; ++gg)
        M = fmaxf(M, part[(size_t)(gg*NPIX + idx)*4]);
    float L = 0.f, SX = 0.f, SY = 0.f;
    #pragma unroll
    for (int gg = 0; gg < NG; ++gg) {
        const float* p = &part[(size_t)(gg*NPIX + idx)*4];
        float e = __expf((p[0] - M)*SCALE);
        L  += p[1]*e;
        SX += p[2]*e;
        SY += p[3]*e;
    }
    int b = idx / PLANE, rem = idx % PLANE;
    out[(b*2 + 0)*PLANE + rem] = SX / L;
    out[(b*2 + 1)*PLANE + rem] = SY / L;
}

extern "C" void kernel_launch(void* const* d_in, const int* in_sizes, int n_in,
                              void* d_out, int out_size, void* d_ws, size_t ws_size,
                              hipStream_t stream) {
    const float* in1 = (const float*)d_in[0];
    const float* in2 = (const float*)d_in[1];
    float* out  = (float*)d_out;
    float* inv1 = (float*)d_ws;            // [B*H*W]
    float* inv2 = inv1 + NPIX;             // [B*H*W]
    float* part = inv2 + NPIX;             // [NG][B*H*W][4]  (m, l, sx, sy)

    norm_kernel<<<2*BB*HH, 128, 0, stream>>>(in1, in2, inv1, inv2);
    corr_kernel<<<BB*HH*NG, 128, 0, stream>>>(in1, in2, inv1, inv2, part);
    merge_kernel<<<(NPIX+255)/256, 256, 0, stream>>>(part, out);
}

// Round 2
// 187.883 us; speedup vs baseline: 4.9527x; 4.9527x over previous
//
#include <hip/hip_runtime.h>
#include <math.h>

#define BB 4
#define CC 64
#define HH 112
#define WW 112
#define MD 20
#define KD 41
#define SCALE 10000.0f
#define NPIX (BB*HH*WW)
#define NT 10                 // p-tiles per row (p = w + dyi in [0,160))
#define ROW2 (NT*2*2*64*8)    // in2s ushorts per (b,row): 20480
#define IN2S_BYTES ((size_t)BB*HH*ROW2*2)   // 18,350,080

typedef _Float16 half8   __attribute__((ext_vector_type(8)));
typedef float    f32x4   __attribute__((ext_vector_type(4)));
typedef unsigned short ushort8 __attribute__((ext_vector_type(8)));

static __device__ __forceinline__ unsigned short f2h_bits(float x) {
    _Float16 h = (_Float16)x;
    return __builtin_bit_cast(unsigned short, h);
}
static __device__ __forceinline__ float h2f(unsigned short s) {
    return (float)__builtin_bit_cast(_Float16, s);
}

// Prep: per (b,row): compute inv-norms; write normalized in2 split (hi, lo*4096)
// in MFMA B-fragment order: offset(tau,ks,split,lane,j), value = in2n[c][p-20],
// c = 32ks+8q+j, p = 16tau+n, lane = q*16+n. Zero outside real columns.
// Also write inv1 plane for the main kernel's A build.
__global__ __launch_bounds__(256) void prep_kernel(const float* __restrict__ in1,
                                                   const float* __restrict__ in2,
                                                   unsigned short* __restrict__ in2s,
                                                   float* __restrict__ inv1) {
    __shared__ float sinv2[WW];
    int bid = blockIdx.x;
    int b = bid / HH, h = bid % HH;
    int t = threadIdx.x;

    if (t < WW) {                       // inv2 for this row -> LDS
        float s = 0.f;
        for (int c = 0; c < CC; ++c) {
            float x = in2[((b*CC + c)*HH + h)*WW + t];
            s += x*x;
        }
        sinv2[t] = 1.0f / fmaxf(sqrtf(s), 1e-12f);
    } else if (t >= 128 && t < 128 + WW) {  // inv1 -> global
        int w = t - 128;
        float s = 0.f;
        for (int c = 0; c < CC; ++c) {
            float x = in1[((b*CC + c)*HH + h)*WW + w];
            s += x*x;
        }
        inv1[(b*HH + h)*WW + w] = 1.0f / fmaxf(sqrtf(s), 1e-12f);
    }
    __syncthreads();

    int wave = t >> 6, lane = t & 63;
    int n = lane & 15, q = lane >> 4;
    unsigned short* base = in2s + (size_t)(b*HH + h)*ROW2;
    for (int tsk = wave; tsk < NT*2; tsk += 4) {
        int tau = tsk >> 1, ks = tsk & 1;
        int p = 16*tau + n, col = p - MD;
        ushort8 hb = {0,0,0,0,0,0,0,0}, lb = {0,0,0,0,0,0,0,0};
        if (col >= 0 && col < WW) {
            float iv = sinv2[col];
            #pragma unroll
            for (int j = 0; j < 8; ++j) {
                int c = 32*ks + 8*q + j;
                float x = in2[((b*CC + c)*HH + h)*WW + col] * iv;
                unsigned short xh = f2h_bits(x);
                float r = (x - h2f(xh)) * 4096.0f;
                hb[j] = xh;
                lb[j] = f2h_bits(r);
            }
        }
        *(ushort8*)(base + (size_t)((tau*4 + ks*2 + 0)*64 + lane)*8) = hb;
        *(ushort8*)(base + (size_t)((tau*4 + ks*2 + 1)*64 + lane)*8) = lb;
    }
}

// Main: one wave per (b, h, w-tile). 4 banded MFMA tiles per dx, fp16-split,
// per-lane online softmax, butterfly merge, write flow.
__global__ __launch_bounds__(64, 3) void corr_kernel(const float* __restrict__ in1,
                                                     const unsigned short* __restrict__ in2s,
                                                     const float* __restrict__ inv1,
                                                     float* __restrict__ out) {
    int gid = blockIdx.x;
    int wt  = gid / (BB*HH);            // wt-outer: same-(b,h) tiles share XCD residue
    int rem = gid % (BB*HH);
    int b = rem / HH, h = rem % HH;
    int lane = threadIdx.x;
    int n = lane & 15, q = lane >> 4;
    int m0 = 4*q;                       // C rows m = m0 + r

    // ---- A fragments (A row m = lane&15 -> pixel w = wt*16 + n) ----
    int wA = wt*16 + n;
    float i1 = inv1[(b*HH + h)*WW + wA];
    half8 aH[2], aL[2];
    #pragma unroll
    for (int ks = 0; ks < 2; ++ks) {
        #pragma unroll
        for (int j = 0; j < 8; ++j) {
            int c = 32*ks + 8*q + j;
            float x = in1[((b*CC + c)*HH + h)*WW + wA] * i1;
            _Float16 xh = (_Float16)x;
            aH[ks][j] = xh;
            aL[ks][j] = (_Float16)((x - (float)xh) * 4096.0f);
        }
    }

    // ---- per-r constants: nm = n - m, validity of oi tiles ----
    float nm20[4]; bool v0[4], v2[4], v3[4];
    #pragma unroll
    for (int r = 0; r < 4; ++r) {
        int nm = n - (m0 + r);          // dyi = 16*oi + nm
        nm20[r] = (float)(nm - 20);
        v0[r] = (nm >= 0);
        v2[r] = (nm <= 8);
        v3[r] = (nm <= -8);
    }

    float sm[4], sl[4], ssx[4], ssy[4];
    #pragma unroll
    for (int r = 0; r < 4; ++r) { sm[r] = -3.0f; sl[r] = 0.f; ssx[r] = 0.f; ssy[r] = 0.f; }

    int dlo = max(0, MD - h);
    int dhi = min(KD, HH + MD - h);     // h2 = h+dxi-20 in [0,112)

    for (int dxi = dlo; dxi < dhi; ++dxi) {
        const unsigned short* rb = in2s + (size_t)(b*HH + (h + dxi - MD))*ROW2;
        f32x4 s[4];
        #pragma unroll
        for (int oi = 0; oi < 4; ++oi) {
            int tau = wt + oi;
            const half8* fp = (const half8*)(rb + (size_t)(tau*4*64 + lane)*8);
            half8 bH0 = fp[0];          // (ks0,hi): +0*64 lanes
            half8 bL0 = fp[64];         // (ks0,lo)
            half8 bH1 = fp[128];        // (ks1,hi)
            half8 bL1 = fp[192];        // (ks1,lo)
            f32x4 a0 = {0.f,0.f,0.f,0.f}, a1 = {0.f,0.f,0.f,0.f};
            a0 = __builtin_amdgcn_mfma_f32_16x16x32_f16(aH[0], bH0, a0, 0, 0, 0);
            a1 = __builtin_amdgcn_mfma_f32_16x16x32_f16(aH[0], bL0, a1, 0, 0, 0);
            a1 = __builtin_amdgcn_mfma_f32_16x16x32_f16(aL[0], bH0, a1, 0, 0, 0);
            a0 = __builtin_amdgcn_mfma_f32_16x16x32_f16(aH[1], bH1, a0, 0, 0, 0);
            a1 = __builtin_amdgcn_mfma_f32_16x16x32_f16(aH[1], bL1, a1, 0, 0, 0);
            a1 = __builtin_amdgcn_mfma_f32_16x16x32_f16(aL[1], bH1, a1, 0, 0, 0);
            s[oi] = a0 + a1 * (1.0f/4096.0f);
        }
        float dxf = (float)(dxi - MD);
        #pragma unroll
        for (int r = 0; r < 4; ++r) {
            float s0v = v0[r] ? s[0][r] : -3.0f;
            float s1v = s[1][r];
            float s2v = v2[r] ? s[2][r] : -3.0f;
            float s3v = v3[r] ? s[3][r] : -3.0f;
            float mn = fmaxf(fmaxf(sm[r], s0v), fmaxf(fmaxf(s1v, s2v), s3v));
            float er = __expf((sm[r] - mn)*SCALE);
            float e0 = __expf((s0v - mn)*SCALE);
            float e1 = __expf((s1v - mn)*SCALE);
            float e2 = __expf((s2v - mn)*SCALE);
            float e3 = __expf((s3v - mn)*SCALE);
            float sum = (e0 + e1) + (e2 + e3);
            float tt  = e1 + 2.f*e2 + 3.f*e3;           // sum(oi*e)
            sl[r]  = sl[r]*er + sum;
            ssx[r] = ssx[r]*er + dxf*sum;
            ssy[r] = ssy[r]*er + (16.f*tt + nm20[r]*sum);  // sum(e*(dyi-20))
            sm[r]  = mn;
        }
    }

    // ---- out-of-range dx rows: all 41 sims are exactly 0 ----
    int nlo = dlo, nhi = KD - dhi;
    if (nlo + nhi > 0) {
        // sum of (dxi-20) over skipped dxi
        float sdx = 0.f;
        for (int d = 0; d < nlo; ++d)  sdx += (float)(d - MD);
        for (int d = dhi; d < KD; ++d) sdx += (float)(d - MD);
        float cnt = (float)((nlo + nhi)*KD);
        #pragma unroll
        for (int r = 0; r < 4; ++r) {
            float mn = fmaxf(sm[r], 0.f);
            float er = __expf((sm[r] - mn)*SCALE);
            float e0 = __expf((0.f - mn)*SCALE);
            sl[r]  = sl[r]*er + cnt*e0;
            ssx[r] = ssx[r]*er + (float)KD*sdx*e0;
            ssy[r] = ssy[r]*er;                         // sum(dyi-20) == 0
            sm[r]  = mn;
        }
    }

    // ---- butterfly merge across the 16 n-lanes (same q group) ----
    #pragma unroll
    for (int off = 1; off < 16; off <<= 1) {
        #pragma unroll
        for (int r = 0; r < 4; ++r) {
            float m2 = __shfl_xor(sm[r],  off);
            float l2 = __shfl_xor(sl[r],  off);
            float x2 = __shfl_xor(ssx[r], off);
            float y2 = __shfl_xor(ssy[r], off);
            float mn = fmaxf(sm[r], m2);
            float ea = __expf((sm[r] - mn)*SCALE);
            float eb = __expf((m2    - mn)*SCALE);
            sl[r]  = sl[r]*ea  + l2*eb;
            ssx[r] = ssx[r]*ea + x2*eb;
            ssy[r] = ssy[r]*ea + y2*eb;
            sm[r]  = mn;
        }
    }

    if (n == 0) {
        #pragma unroll
        for (int r = 0; r < 4; ++r) {
            int w = wt*16 + m0 + r;
            out[((b*2 + 0)*HH + h)*WW + w] = ssx[r] / sl[r];
            out[((b*2 + 1)*HH + h)*WW + w] = ssy[r] / sl[r];
        }
    }
}

extern "C" void kernel_launch(void* const* d_in, const int* in_sizes, int n_in,
                              void* d_out, int out_size, void* d_ws, size_t ws_size,
                              hipStream_t stream) {
    const float* in1 = (const float*)d_in[0];
    const float* in2 = (const float*)d_in[1];
    float* out = (float*)d_out;
    unsigned short* in2s = (unsigned short*)d_ws;
    float* inv1 = (float*)((char*)d_ws + IN2S_BYTES);

    prep_kernel<<<BB*HH, 256, 0, stream>>>(in1, in2, in2s, inv1);
    corr_kernel<<<7*BB*HH, 64, 0, stream>>>(in1, in2s, inv1, out);
}

// Round 4
// 183.904 us; speedup vs baseline: 5.0598x; 1.0216x over previous
//
#include <hip/hip_runtime.h>

#define BB 4
#define CC 64
#define HH 112
#define WW 112
#define MD 20
#define KD 41
#define S2 14426.950408f      // (1/TEMP) * log2(e); use with ex2()
#define NPIX (BB*HH*WW)
#define NT 10                 // p-tiles per row (p = w + dyi in [0,160))
#define ROW2 (NT*2*2*64*8)    // in2s ushorts per (b,row): 20480
#define IN2S_BYTES ((size_t)BB*HH*ROW2*2)   // 18,350,080

typedef _Float16 half8   __attribute__((ext_vector_type(8)));
typedef float    f32x4   __attribute__((ext_vector_type(4)));
typedef unsigned short ushort8 __attribute__((ext_vector_type(8)));

static __device__ __forceinline__ float ex2(float x) {
    return __builtin_amdgcn_exp2f(x);        // v_exp_f32
}
static __device__ __forceinline__ unsigned short f2h_bits(float x) {
    _Float16 h = (_Float16)x;
    return __builtin_bit_cast(unsigned short, h);
}
static __device__ __forceinline__ float h2f(unsigned short s) {
    return (float)__builtin_bit_cast(_Float16, s);
}
static __device__ __forceinline__ float fmax_f(float a, float b) { return a > b ? a : b; }

// ---- inverse L2 norms per pixel (coalesced across w) ----
__global__ __launch_bounds__(128) void norm_kernel(const float* __restrict__ in1,
                                                   const float* __restrict__ in2,
                                                   float* __restrict__ inv1,
                                                   float* __restrict__ inv2) {
    int bid = blockIdx.x;              // [0, 2*B*H)
    int which = bid / (BB*HH);
    int rem = bid % (BB*HH);
    int b = rem / HH, h = rem % HH;
    int t = threadIdx.x;
    if (t >= WW) return;
    const float* src = which ? in2 : in1;
    float s = 0.f;
    #pragma unroll
    for (int c = 0; c < CC; ++c) {
        float x = src[((b*CC + c)*HH + h)*WW + t];
        s += x*x;
    }
    float inv = 1.0f / fmax_f(__builtin_sqrtf(s), 1e-12f);
    (which ? inv2 : inv1)[(b*HH + h)*WW + t] = inv;
}

// ---- pack normalized, fp16-split in2 into MFMA B-fragment order ----
// One wave per (b,h,tau). LDS-transposed so global reads are coalesced and
// fragment stores are vector 16B. value(c, p=16tau+n) at
// offset ((tau*4 + ks*2 + split)*64 + lane)*8 ushorts, c = 32ks+8q+j.
__global__ __launch_bounds__(64) void pack_kernel(const float* __restrict__ in2,
                                                  const float* __restrict__ inv2,
                                                  unsigned short* __restrict__ in2s) {
    __shared__ float tile[CC][17];     // +1 pad
    int bid = blockIdx.x;
    int tau = bid % NT;
    int bh  = bid / NT;
    int b = bh / HH, h = bh % HH;
    int lane = threadIdx.x;
    int n = lane & 15, q = lane >> 4;
    int col0 = 16*tau - MD;

    // load the 64ch x 16col tile (zero-padded)
    #pragma unroll
    for (int it = 0; it < 4; ++it) {
        int c  = it*16 + (lane >> 2);
        int k0 = (lane & 3) * 4;
        const float* src = &in2[((b*CC + c)*HH + h)*WW];
        #pragma unroll
        for (int u = 0; u < 4; ++u) {
            int cw = col0 + k0 + u;
            tile[c][k0 + u] = (cw >= 0 && cw < WW) ? src[cw] : 0.f;
        }
    }
    __syncthreads();

    int col = col0 + n;
    float iv = (col >= 0 && col < WW) ? inv2[(b*HH + h)*WW + col] : 0.f;
    unsigned short* base = in2s + (size_t)(b*HH + h)*ROW2;
    #pragma unroll
    for (int ks = 0; ks < 2; ++ks) {
        ushort8 hb, lb;
        #pragma unroll
        for (int j = 0; j < 8; ++j) {
            int c = 32*ks + 8*q + j;
            float x = tile[c][n] * iv;
            unsigned short xh = f2h_bits(x);
            hb[j] = xh;
            lb[j] = f2h_bits((x - h2f(xh)) * 4096.0f);
        }
        *(ushort8*)(base + (size_t)((tau*4 + ks*2 + 0)*64 + lane)*8) = hb;
        *(ushort8*)(base + (size_t)((tau*4 + ks*2 + 1)*64 + lane)*8) = lb;
    }
}

// ---- main: one wave per (b,h,wt,dxgroup). XCD-pinned by (b, h-half). ----
__global__ __launch_bounds__(64, 3) void corr_kernel(const float* __restrict__ in1,
                                                     const unsigned short* __restrict__ in2s,
                                                     const float* __restrict__ inv1,
                                                     float* __restrict__ part) {
    int gid = blockIdx.x;
    int xcd  = gid & 7;                 // heuristic: blockIdx%8 -> XCD
    int slot = gid >> 3;                // 0..783
    int hloc = slot % 56;               // consecutive slots walk h (L2 locality)
    int tmp  = slot / 56;               // 0..13
    int dg = tmp & 1;
    int wt = tmp >> 1;                  // 0..6
    int b  = xcd >> 1;
    int h  = (xcd & 1)*56 + hloc;
    int lane = threadIdx.x;
    int n = lane & 15, q = lane >> 4;
    int m0 = 4*q;

    // A fragments (pixel w = wt*16 + n), fp16 split
    int wA = wt*16 + n;
    float i1 = inv1[(b*HH + h)*WW + wA];
    half8 aH[2], aL[2];
    #pragma unroll
    for (int ks = 0; ks < 2; ++ks) {
        #pragma unroll
        for (int j = 0; j < 8; ++j) {
            int c = 32*ks + 8*q + j;
            float x = in1[((b*CC + c)*HH + h)*WW + wA] * i1;
            _Float16 xh = (_Float16)x;
            aH[ks][j] = xh;
            aL[ks][j] = (_Float16)((x - (float)xh) * 4096.0f);
        }
    }

    float nm20[4]; bool v0[4], v2[4], v3[4];
    #pragma unroll
    for (int r = 0; r < 4; ++r) {
        int nm = n - (m0 + r);          // dyi = 16*oi + nm
        nm20[r] = (float)(nm - 20);
        v0[r] = (nm >= 0);
        v2[r] = (nm <= 8);
        v3[r] = (nm <= -8);
    }

    float sm[4], sl[4], ssx[4], ssy[4];
    #pragma unroll
    for (int r = 0; r < 4; ++r) { sm[r] = -3.0f; sl[r] = 0.f; ssx[r] = 0.f; ssy[r] = 0.f; }

    int glo = dg ? 21 : 0;
    int ghi = dg ? KD : 21;
    int lo = glo > (MD - h) ? glo : (MD - h);
    int hi0 = HH + MD - h;
    int hi = ghi < hi0 ? ghi : hi0;
    if (hi < lo) { lo = ghi; hi = ghi; } // whole group out of range

    for (int dxi = lo; dxi < hi; ++dxi) {
        const unsigned short* rb = in2s + (size_t)(b*HH + (h + dxi - MD))*ROW2;
        // batch all 16 fragment loads so they issue back-to-back
        half8 bf[4][4];
        #pragma unroll
        for (int oi = 0; oi < 4; ++oi) {
            const half8* fp = (const half8*)(rb + (size_t)((wt+oi)*4*64 + lane)*8);
            bf[oi][0] = fp[0];    // ks0 hi
            bf[oi][1] = fp[64];   // ks0 lo
            bf[oi][2] = fp[128];  // ks1 hi
            bf[oi][3] = fp[192];  // ks1 lo
        }
        f32x4 s[4];
        #pragma unroll
        for (int oi = 0; oi < 4; ++oi) {
            f32x4 a0 = {0.f,0.f,0.f,0.f}, a1 = {0.f,0.f,0.f,0.f};
            a0 = __builtin_amdgcn_mfma_f32_16x16x32_f16(aH[0], bf[oi][0], a0, 0, 0, 0);
            a1 = __builtin_amdgcn_mfma_f32_16x16x32_f16(aH[0], bf[oi][1], a1, 0, 0, 0);
            a1 = __builtin_amdgcn_mfma_f32_16x16x32_f16(aL[0], bf[oi][0], a1, 0, 0, 0);
            a0 = __builtin_amdgcn_mfma_f32_16x16x32_f16(aH[1], bf[oi][2], a0, 0, 0, 0);
            a1 = __builtin_amdgcn_mfma_f32_16x16x32_f16(aH[1], bf[oi][3], a1, 0, 0, 0);
            a1 = __builtin_amdgcn_mfma_f32_16x16x32_f16(aL[1], bf[oi][2], a1, 0, 0, 0);
            s[oi] = a0 + a1 * (1.0f/4096.0f);
        }
        float dxf = (float)(dxi - MD);
        #pragma unroll
        for (int r = 0; r < 4; ++r) {
            float s0v = v0[r] ? s[0][r] : -3.0f;
            float s1v = s[1][r];
            float s2v = v2[r] ? s[2][r] : -3.0f;
            float s3v = v3[r] ? s[3][r] : -3.0f;
            float mn = fmax_f(fmax_f(sm[r], s0v), fmax_f(fmax_f(s1v, s2v), s3v));
            float er = ex2((sm[r] - mn)*S2);
            float e0 = ex2((s0v - mn)*S2);
            float e1 = ex2((s1v - mn)*S2);
            float e2 = ex2((s2v - mn)*S2);
            float e3 = ex2((s3v - mn)*S2);
            float sum = (e0 + e1) + (e2 + e3);
            float tt  = e1 + 2.f*e2 + 3.f*e3;
            sl[r]  = sl[r]*er + sum;
            ssx[r] = ssx[r]*er + dxf*sum;
            ssy[r] = ssy[r]*er + (16.f*tt + nm20[r]*sum);
            sm[r]  = mn;
        }
    }

    // skipped (out-of-image) dx rows in this group: all 41 sims exactly 0
    int cnt_i = (lo - glo) + (ghi - hi);
    if (cnt_i > 0) {
        float sdx = (float)(lo - glo) * (0.5f*(float)(glo + lo - 1) - (float)MD)
                  + (float)(ghi - hi) * (0.5f*(float)(ghi + hi - 1) - (float)MD);
        float cnt = (float)cnt_i * (float)KD;
        #pragma unroll
        for (int r = 0; r < 4; ++r) {
            float mn = fmax_f(sm[r], 0.f);
            float er = ex2((sm[r] - mn)*S2);
            float e0 = ex2((0.f - mn)*S2);
            sl[r]  = sl[r]*er + cnt*e0;
            ssx[r] = ssx[r]*er + (float)KD*sdx*e0;
            ssy[r] = ssy[r]*er;
            sm[r]  = mn;
        }
    }

    // butterfly merge across the 16 n-lanes
    #pragma unroll
    for (int off = 1; off < 16; off <<= 1) {
        #pragma unroll
        for (int r = 0; r < 4; ++r) {
            float m2 = __shfl_xor(sm[r],  off);
            float l2 = __shfl_xor(sl[r],  off);
            float x2 = __shfl_xor(ssx[r], off);
            float y2 = __shfl_xor(ssy[r], off);
            float mn = fmax_f(sm[r], m2);
            float ea = ex2((sm[r] - mn)*S2);
            float eb = ex2((m2    - mn)*S2);
            sl[r]  = sl[r]*ea  + l2*eb;
            ssx[r] = ssx[r]*ea + x2*eb;
            ssy[r] = ssy[r]*ea + y2*eb;
            sm[r]  = mn;
        }
    }

    if (n == 0) {
        #pragma unroll
        for (int r = 0; r < 4; ++r) {
            int w = wt*16 + m0 + r;
            int pix = (b*HH + h)*WW + w;
            float* p = &part[(size_t)(dg*NPIX + pix)*4];
            p[0] = sm[r]; p[1] = sl[r]; p[2] = ssx[r]; p[3] = ssy[r];
        }
    }
}

// ---- merge the 2 dx-group partials, emit flow ----
__global__ __launch_bounds__(256) void merge_kernel(const float* __restrict__ part,
                                                    float* __restrict__ out) {
    int idx = blockIdx.x*256 + threadIdx.x;
    if (idx >= NPIX) return;
    const float* p0 = &part[(size_t)idx*4];
    const float* p1 = &part[(size_t)(NPIX + idx)*4];
    float M = fmax_f(p0[0], p1[0]);
    float e0 = ex2((p0[0] - M)*S2);
    float e1 = ex2((p1[0] - M)*S2);
    float L  = p0[1]*e0 + p1[1]*e1;
    float SX = p0[2]*e0 + p1[2]*e1;
    float SY = p0[3]*e0 + p1[3]*e1;
    int b = idx / (HH*WW), rem = idx % (HH*WW);
    out[(b*2 + 0)*(HH*WW) + rem] = SX / L;
    out[(b*2 + 1)*(HH*WW) + rem] = SY / L;
}

extern "C" void kernel_launch(void* const* d_in, const int* in_sizes, int n_in,
                              void* d_out, int out_size, void* d_ws, size_t ws_size,
                              hipStream_t stream) {
    const float* in1 = (const float*)d_in[0];
    const float* in2 = (const float*)d_in[1];
    float* out = (float*)d_out;
    unsigned short* in2s = (unsigned short*)d_ws;
    float* inv1 = (float*)((char*)d_ws + IN2S_BYTES);
    float* inv2 = inv1 + NPIX;
    float* part = inv2 + NPIX;          // [2][NPIX][4]

    norm_kernel <<<2*BB*HH, 128, 0, stream>>>(in1, in2, inv1, inv2);
    pack_kernel <<<BB*HH*NT, 64, 0, stream>>>(in2, inv2, in2s);
    corr_kernel <<<8*784, 64, 0, stream>>>(in1, in2s, inv1, part);
    merge_kernel<<<(NPIX+255)/256, 256, 0, stream>>>(part, out);
}

// Round 5
// 165.191 us; speedup vs baseline: 5.6330x; 1.1133x over previous
//
#include <hip/hip_runtime.h>

#define BB 4
#define CC 64
#define HH 112
#define WW 112
#define MD 20
#define KD 41
#define S2 14426.950408f      // (1/TEMP) * log2(e)
#define NT 10                 // p-tiles per row (p = w + dyi in [0,160))
#define ROW2 (NT*2*2*64*8)    // in2s ushorts per (b,row): 20480

typedef _Float16 half8   __attribute__((ext_vector_type(8)));
typedef float    f32x4   __attribute__((ext_vector_type(4)));
typedef unsigned short ushort8 __attribute__((ext_vector_type(8)));

static __device__ __forceinline__ float fmax_f(float a, float b) { return a > b ? a : b; }
static __device__ __forceinline__ unsigned short f2h_bits(float x) {
    _Float16 h = (_Float16)x;
    return __builtin_bit_cast(unsigned short, h);
}
static __device__ __forceinline__ float h2f(unsigned short s) {
    return (float)__builtin_bit_cast(_Float16, s);
}
static __device__ __forceinline__ f32x4 vmax4(f32x4 a, f32x4 b) {
    f32x4 r;
    #pragma unroll
    for (int k = 0; k < 4; ++k) r[k] = a[k] > b[k] ? a[k] : b[k];
    return r;
}
static __device__ __forceinline__ f32x4 vexp4(f32x4 d) {
    f32x4 r;
    #pragma unroll
    for (int k = 0; k < 4; ++k) r[k] = __builtin_amdgcn_exp2f(d[k]);
    return r;
}
static __device__ __forceinline__ f32x4 mfma16(half8 a, half8 b, f32x4 c) {
    return __builtin_amdgcn_mfma_f32_16x16x32_f16(a, b, c, 0, 0, 0);
}

// ---- pack: per (b,h): stage in2 row in LDS, compute inv2 in-kernel, emit
// normalized fp16-split fragments in MFMA B order. 448 blocks x 256. ----
__global__ __launch_bounds__(256) void pack_kernel(const float* __restrict__ in2,
                                                   unsigned short* __restrict__ in2s) {
    __shared__ float tile[CC][WW + 1];   // 64 x 113 floats (pad: conflict-free col reads)
    __shared__ float sinv[WW];
    int b = blockIdx.x / HH, h = blockIdx.x % HH;
    int t = threadIdx.x;
    const float* src = in2 + ((size_t)(b*CC)*HH + h)*WW;   // + c*HH*WW + w

    for (int i = t; i < CC*WW; i += 256) {
        int c = i / WW, w = i % WW;
        tile[c][w] = src[(size_t)c*(HH*WW) + w];           // coalesced in w
    }
    __syncthreads();
    if (t < WW) {
        float s = 0.f;
        #pragma unroll
        for (int c = 0; c < CC; ++c) { float x = tile[c][t]; s += x*x; }
        sinv[t] = 1.0f / fmax_f(__builtin_sqrtf(s), 1e-12f);
    }
    __syncthreads();

    int wv = t >> 6, lane = t & 63;
    int n = lane & 15, q = lane >> 4;
    unsigned short* base = in2s + (size_t)(b*HH + h)*ROW2;
    for (int u = wv; u < NT*2; u += 4) {
        int tau = u >> 1, ks = u & 1;
        int col = 16*tau + n - MD;
        ushort8 hb = {0,0,0,0,0,0,0,0}, lb = {0,0,0,0,0,0,0,0};
        if (col >= 0 && col < WW) {
            float iv = sinv[col];
            #pragma unroll
            for (int j = 0; j < 8; ++j) {
                int c = 32*ks + 8*q + j;
                float x = tile[c][col] * iv;
                unsigned short xh = f2h_bits(x);
                hb[j] = xh;
                lb[j] = f2h_bits((x - h2f(xh)) * 4096.0f);
            }
        }
        *(ushort8*)(base + (size_t)((tau*4 + ks*2 + 0)*64 + lane)*8) = hb;
        *(ushort8*)(base + (size_t)((tau*4 + ks*2 + 1)*64 + lane)*8) = lb;
    }
}

// ---- corr: 2-wave block = (b, p, wt); wave wv handles h = p + 56*wv.
// In-wave inv1 (q-butterfly), all 41 dx, f32x4 softmax, direct flow write. ----
__global__ __launch_bounds__(128) void corr_kernel(const float* __restrict__ in1,
                                                   const unsigned short* __restrict__ in2s,
                                                   float* __restrict__ out) {
    int gid = blockIdx.x;
    int xcd = gid & 7;                   // blockIdx%8 -> XCD
    int s   = gid >> 3;                  // [0,196)
    int b   = xcd >> 1;
    int p   = (xcd & 1)*28 + (s % 28);   // XCD pinned to a (b, quarter-h) slab
    int wt  = s / 28;                    // [0,7)
    int wv  = threadIdx.x >> 6;
    int h   = p + 56*wv;                 // pair (h, h+56): balances durations
    int lane = threadIdx.x & 63;
    int n = lane & 15, q = lane >> 4;
    int m0 = 4*q;
    int wA = wt*16 + n;

    // ---- load in1 channels; inv1 via q-butterfly; build split A fragments ----
    const float* a_src = in1 + ((size_t)(b*CC)*HH + h)*WW + wA;
    float x[16];
    float ss = 0.f;
    #pragma unroll
    for (int ks = 0; ks < 2; ++ks)
        #pragma unroll
        for (int j = 0; j < 8; ++j) {
            float v = a_src[(size_t)(32*ks + 8*q + j)*(HH*WW)];
            x[ks*8 + j] = v;
            ss += v*v;
        }
    ss += __shfl_xor(ss, 16);            // sum over q (lanes ^16, ^32): full 64-ch norm
    ss += __shfl_xor(ss, 32);
    float i1 = 1.0f / fmax_f(__builtin_sqrtf(ss), 1e-12f);
    half8 aH[2], aL[2];
    #pragma unroll
    for (int ks = 0; ks < 2; ++ks)
        #pragma unroll
        for (int j = 0; j < 8; ++j) {
            float v = x[ks*8 + j] * i1;
            _Float16 vh = (_Float16)v;
            aH[ks][j] = vh;
            aL[ks][j] = (_Float16)((v - (float)vh) * 4096.0f);
        }

    // ---- per-r constants ----
    f32x4 NM20; bool v0b[4], v2b[4], v3b[4];
    #pragma unroll
    for (int r = 0; r < 4; ++r) {
        int nm = n - (m0 + r);           // dyi = 16*oi + nm
        NM20[r] = (float)(nm - 20);
        v0b[r] = (nm >= 0);
        v2b[r] = (nm <= 8);
        v3b[r] = (nm <= -8);
    }

    f32x4 SM = {-4.f,-4.f,-4.f,-4.f}, SL = {0.f,0.f,0.f,0.f};
    f32x4 SSX = {0.f,0.f,0.f,0.f}, SSY = {0.f,0.f,0.f,0.f};

    int dlo = MD - h > 0 ? MD - h : 0;
    int dhi = (HH + MD - h) < KD ? (HH + MD - h) : KD;

    for (int dxi = dlo; dxi < dhi; ++dxi) {
        const unsigned short* rb = in2s + (size_t)(b*HH + (h + dxi - MD))*ROW2;
        half8 bf[4][4];
        #pragma unroll
        for (int oi = 0; oi < 4; ++oi) {
            const half8* fp = (const half8*)(rb + (size_t)((wt + oi)*4*64 + lane)*8);
            bf[oi][0] = fp[0];    // ks0 hi
            bf[oi][1] = fp[64];   // ks0 lo
            bf[oi][2] = fp[128];  // ks1 hi
            bf[oi][3] = fp[192];  // ks1 lo
        }
        f32x4 sv[4];
        #pragma unroll
        for (int oi = 0; oi < 4; ++oi) {
            f32x4 a0 = {0.f,0.f,0.f,0.f}, a1 = {0.f,0.f,0.f,0.f};
            a0 = mfma16(aH[0], bf[oi][0], a0);
            a1 = mfma16(aH[0], bf[oi][1], a1);
            a1 = mfma16(aL[0], bf[oi][0], a1);
            a0 = mfma16(aH[1], bf[oi][2], a0);
            a1 = mfma16(aH[1], bf[oi][3], a1);
            a1 = mfma16(aL[1], bf[oi][2], a1);
            sv[oi] = a0 + a1 * (1.0f/4096.0f);     // vector fma
        }
        // validity masks (dyi in [0,40])
        f32x4 V0, V1 = sv[1], V2, V3;
        #pragma unroll
        for (int r = 0; r < 4; ++r) {
            V0[r] = v0b[r] ? sv[0][r] : -4.0f;
            V2[r] = v2b[r] ? sv[2][r] : -4.0f;
            V3[r] = v3b[r] ? sv[3][r] : -4.0f;
        }
        f32x4 MN = vmax4(vmax4(SM, V0), vmax4(V1, vmax4(V2, V3)));
        f32x4 ER = vexp4((SM - MN) * S2);
        f32x4 E0 = vexp4((V0 - MN) * S2);
        f32x4 E1 = vexp4((V1 - MN) * S2);
        f32x4 E2 = vexp4((V2 - MN) * S2);
        f32x4 E3 = vexp4((V3 - MN) * S2);
        f32x4 SUM = (E0 + E1) + (E2 + E3);
        f32x4 TT  = E1 + E2*2.0f + E3*3.0f;        // sum(oi*e)
        float dxf = (float)(dxi - MD);
        SL  = SL *ER + SUM;
        SSX = SSX*ER + SUM*dxf;
        SSY = SSY*ER + (TT*16.0f + NM20*SUM);      // sum(e*(dyi-20))
        SM  = MN;
    }

    // out-of-image dx rows: all 41 sims exactly 0
    int miss = dlo + (KD - dhi);
    if (miss > 0) {
        float sdx = 0.f;
        for (int d = 0; d < dlo; ++d)  sdx += (float)(d - MD);
        for (int d = dhi; d < KD; ++d) sdx += (float)(d - MD);
        float cnt = (float)miss * (float)KD;
        f32x4 Z = {0.f,0.f,0.f,0.f};
        f32x4 MN = vmax4(SM, Z);
        f32x4 ER = vexp4((SM - MN) * S2);
        f32x4 E0 = vexp4((Z  - MN) * S2);
        SL  = SL *ER + E0*cnt;
        SSX = SSX*ER + E0*((float)KD*sdx);
        SSY = SSY*ER;
        SM  = MN;
    }

    // butterfly merge across the 16 n-lanes
    #pragma unroll
    for (int off = 1; off < 16; off <<= 1) {
        f32x4 M2, L2, X2, Y2;
        #pragma unroll
        for (int k = 0; k < 4; ++k) {
            M2[k] = __shfl_xor(SM[k],  off);
            L2[k] = __shfl_xor(SL[k],  off);
            X2[k] = __shfl_xor(SSX[k], off);
            Y2[k] = __shfl_xor(SSY[k], off);
        }
        f32x4 MN = vmax4(SM, M2);
        f32x4 EA = vexp4((SM - MN) * S2);
        f32x4 EB = vexp4((M2 - MN) * S2);
        SL  = SL *EA + L2*EB;
        SSX = SSX*EA + X2*EB;
        SSY = SSY*EA + Y2*EB;
        SM  = MN;
    }

    if (n == 0) {
        #pragma unroll
        for (int r = 0; r < 4; ++r) {
            int w = wt*16 + m0 + r;
            out[((b*2 + 0)*HH + h)*WW + w] = SSX[r] / SL[r];
            out[((b*2 + 1)*HH + h)*WW + w] = SSY[r] / SL[r];
        }
    }
}

extern "C" void kernel_launch(void* const* d_in, const int* in_sizes, int n_in,
                              void* d_out, int out_size, void* d_ws, size_t ws_size,
                              hipStream_t stream) {
    const float* in1 = (const float*)d_in[0];
    const float* in2 = (const float*)d_in[1];
    float* out = (float*)d_out;
    unsigned short* in2s = (unsigned short*)d_ws;

    pack_kernel<<<BB*HH, 256, 0, stream>>>(in2, in2s);
    corr_kernel<<<8*196, 128, 0, stream>>>(in1, in2s, out);
}

// Round 6
// 157.295 us; speedup vs baseline: 5.9158x; 1.0502x over previous
//
#include <hip/hip_runtime.h>

#define BB 4
#define CC 64
#define HH 112
#define WW 112
#define MD 20
#define KD 41
#define S2 14426.950408f      // (1/TEMP) * log2(e): sims pre-scaled into exp2 domain
#define NPIX (BB*HH*WW)
#define NT 10                 // p-tiles per row (p = w + dyi in [0,160))
#define ROW2 (NT*2*2*64*8)    // in2s ushorts per (b,row): 20480
#define IN2S_BYTES ((size_t)BB*HH*ROW2*2)   // 18,350,080
#define NEG (-60000.0f)       // "minus infinity" in scaled domain

typedef _Float16 half8   __attribute__((ext_vector_type(8)));
typedef float    f32x4   __attribute__((ext_vector_type(4)));
typedef unsigned short ushort8 __attribute__((ext_vector_type(8)));

static __device__ __forceinline__ float fmax_f(float a, float b) { return a > b ? a : b; }
static __device__ __forceinline__ unsigned short f2h_bits(float x) {
    _Float16 h = (_Float16)x;
    return __builtin_bit_cast(unsigned short, h);
}
static __device__ __forceinline__ float h2f(unsigned short s) {
    return (float)__builtin_bit_cast(_Float16, s);
}
static __device__ __forceinline__ f32x4 vmax4(f32x4 a, f32x4 b) {
    f32x4 r;
    #pragma unroll
    for (int k = 0; k < 4; ++k) r[k] = a[k] > b[k] ? a[k] : b[k];
    return r;
}
static __device__ __forceinline__ f32x4 vexp4(f32x4 d) {   // d already scaled
    f32x4 r;
    #pragma unroll
    for (int k = 0; k < 4; ++k) r[k] = __builtin_amdgcn_exp2f(d[k]);
    return r;
}
static __device__ __forceinline__ f32x4 mfma16(half8 a, half8 b, f32x4 c) {
    return __builtin_amdgcn_mfma_f32_16x16x32_f16(a, b, c, 0, 0, 0);
}

// ---- pack: one wave per (b,h,tau). No LDS. Each lane owns one column and
// 16 channels; column norm via q-butterfly (lanes ^16,^32 share the column).
// Emits normalized fp16-split B fragments: offset ((tau*4+ks*2+split)*64+lane)*8. ----
__global__ __launch_bounds__(256) void pack_kernel(const float* __restrict__ in2,
                                                   unsigned short* __restrict__ in2s) {
    int wid = blockIdx.x*4 + (threadIdx.x >> 6);   // [0, 4480)
    int lane = threadIdx.x & 63;
    int tau = wid % NT;
    int bh  = wid / NT;
    int b = bh / HH, h = bh % HH;
    int n = lane & 15, q = lane >> 4;
    int col = 16*tau + n - MD;
    bool ok = (col >= 0 && col < WW);
    int colc = ok ? col : 0;
    const float* src = in2 + ((size_t)(b*CC)*HH + h)*WW + colc;

    float x[16];
    float ss = 0.f;
    #pragma unroll
    for (int ks = 0; ks < 2; ++ks)
        #pragma unroll
        for (int j = 0; j < 8; ++j) {
            float v = ok ? src[(size_t)(32*ks + 8*q + j)*(HH*WW)] : 0.f;
            x[ks*8 + j] = v;
            ss += v*v;
        }
    ss += __shfl_xor(ss, 16);       // q-butterfly: full 64-ch column norm
    ss += __shfl_xor(ss, 32);
    float iv = 1.0f / fmax_f(__builtin_sqrtf(ss), 1e-12f);

    unsigned short* base = in2s + (size_t)(b*HH + h)*ROW2;
    #pragma unroll
    for (int ks = 0; ks < 2; ++ks) {
        ushort8 hb, lb;
        #pragma unroll
        for (int j = 0; j < 8; ++j) {
            float v = x[ks*8 + j] * iv;          // 0 for invalid cols
            unsigned short vh = f2h_bits(v);
            hb[j] = vh;
            lb[j] = f2h_bits((v - h2f(vh)) * 4096.0f);
        }
        *(ushort8*)(base + (size_t)((tau*4 + ks*2 + 0)*64 + lane)*8) = hb;
        *(ushort8*)(base + (size_t)((tau*4 + ks*2 + 1)*64 + lane)*8) = lb;
    }
}

// ---- corr: block = 7 waves, all same (b,h,dxg); wave wv = wt. dx-split x3
// raises total waves to 9408 (vs 3136) for latency hiding. Exact partial
// online softmax in scaled (exp2) domain; partials merged by merge_kernel. ----
__global__ __launch_bounds__(448) void corr_kernel(const float* __restrict__ in1,
                                                   const unsigned short* __restrict__ in2s,
                                                   float* __restrict__ part) {
    int gid = blockIdx.x;               // [0, 1344)
    int xcd  = gid & 7;                 // blockIdx%8 -> XCD (L2 slab pinning)
    int slot = gid >> 3;                // [0, 168)
    int hloc = slot % 56;
    int g    = slot / 56;               // dx group [0,3)
    int b    = xcd >> 1;
    int h    = (xcd & 1)*56 + hloc;
    int wt   = threadIdx.x >> 6;        // wave = w-tile, 0..6
    int lane = threadIdx.x & 63;
    int n = lane & 15, q = lane >> 4;
    int m0 = 4*q;
    int wA = wt*16 + n;

    // ---- in1 channels; inv1 via q-butterfly; split A fragments ----
    const float* a_src = in1 + ((size_t)(b*CC)*HH + h)*WW + wA;
    float x[16];
    float ss = 0.f;
    #pragma unroll
    for (int ks = 0; ks < 2; ++ks)
        #pragma unroll
        for (int j = 0; j < 8; ++j) {
            float v = a_src[(size_t)(32*ks + 8*q + j)*(HH*WW)];
            x[ks*8 + j] = v;
            ss += v*v;
        }
    ss += __shfl_xor(ss, 16);
    ss += __shfl_xor(ss, 32);
    float i1 = 1.0f / fmax_f(__builtin_sqrtf(ss), 1e-12f);
    half8 aH[2], aL[2];
    #pragma unroll
    for (int ks = 0; ks < 2; ++ks)
        #pragma unroll
        for (int j = 0; j < 8; ++j) {
            float v = x[ks*8 + j] * i1;
            _Float16 vh = (_Float16)v;
            aH[ks][j] = vh;
            aL[ks][j] = (_Float16)((v - (float)vh) * 4096.0f);
        }

    // ---- per-r constants (dyi = 16*oi + n - m) ----
    f32x4 NM20; bool v0b[4], v2b[4], v3b[4];
    #pragma unroll
    for (int r = 0; r < 4; ++r) {
        int nm = n - (m0 + r);
        NM20[r] = (float)(nm - 20);
        v0b[r] = (nm >= 0);
        v2b[r] = (nm <= 8);
        v3b[r] = (nm <= -8);
    }

    f32x4 SM = {NEG,NEG,NEG,NEG}, SL = {0.f,0.f,0.f,0.f};
    f32x4 SSX = {0.f,0.f,0.f,0.f}, SSY = {0.f,0.f,0.f,0.f};

    int glo = g*14;
    int ghi = glo + 14 < KD ? glo + 14 : KD;    // 14,14,13
    int lo = glo > (MD - h) ? glo : (MD - h);
    int hi0 = HH + MD - h;
    int hi = ghi < hi0 ? ghi : hi0;
    if (hi < lo) { lo = ghi; hi = ghi; }        // whole group out of image

    for (int dxi = lo; dxi < hi; ++dxi) {
        const unsigned short* rb = in2s + (size_t)(b*HH + (h + dxi - MD))*ROW2;
        half8 bf[4][4];
        #pragma unroll
        for (int oi = 0; oi < 4; ++oi) {
            const half8* fp = (const half8*)(rb + (size_t)((wt + oi)*4*64 + lane)*8);
            bf[oi][0] = fp[0];    // ks0 hi
            bf[oi][1] = fp[64];   // ks0 lo
            bf[oi][2] = fp[128];  // ks1 hi
            bf[oi][3] = fp[192];  // ks1 lo
        }
        f32x4 sv[4];
        #pragma unroll
        for (int oi = 0; oi < 4; ++oi) {
            f32x4 a0 = {0.f,0.f,0.f,0.f}, a1 = {0.f,0.f,0.f,0.f};
            a0 = mfma16(aH[0], bf[oi][0], a0);
            a1 = mfma16(aH[0], bf[oi][1], a1);
            a1 = mfma16(aL[0], bf[oi][0], a1);
            a0 = mfma16(aH[1], bf[oi][2], a0);
            a1 = mfma16(aH[1], bf[oi][3], a1);
            a1 = mfma16(aL[1], bf[oi][2], a1);
            sv[oi] = a0*S2 + a1*(S2/4096.0f);   // pre-scaled into exp2 domain
        }
        f32x4 V0, V1 = sv[1], V2, V3;
        #pragma unroll
        for (int r = 0; r < 4; ++r) {
            V0[r] = v0b[r] ? sv[0][r] : NEG;
            V2[r] = v2b[r] ? sv[2][r] : NEG;
            V3[r] = v3b[r] ? sv[3][r] : NEG;
        }
        f32x4 MN = vmax4(vmax4(SM, V0), vmax4(V1, vmax4(V2, V3)));
        f32x4 ER = vexp4(SM - MN);
        f32x4 E0 = vexp4(V0 - MN);
        f32x4 E1 = vexp4(V1 - MN);
        f32x4 E2 = vexp4(V2 - MN);
        f32x4 E3 = vexp4(V3 - MN);
        f32x4 SUM = (E0 + E1) + (E2 + E3);
        f32x4 TT  = E1 + E2*2.0f + E3*3.0f;
        float dxf = (float)(dxi - MD);
        SL  = SL *ER + SUM;
        SSX = SSX*ER + SUM*dxf;
        SSY = SSY*ER + (TT*16.0f + NM20*SUM);
        SM  = MN;
    }

    // out-of-image dx rows in this group: all 41 sims exactly 0 (scaled: 0)
    int miss = (lo - glo) + (ghi - hi);
    if (miss > 0) {
        float sdx = 0.f;
        for (int d = glo; d < lo; ++d)  sdx += (float)(d - MD);
        for (int d = hi; d < ghi; ++d)  sdx += (float)(d - MD);
        float cnt = (float)miss * (float)KD;
        f32x4 Z = {0.f,0.f,0.f,0.f};
        f32x4 MN = vmax4(SM, Z);
        f32x4 ER = vexp4(SM - MN);
        f32x4 E0 = vexp4(Z  - MN);
        SL  = SL *ER + E0*cnt;
        SSX = SSX*ER + E0*((float)KD*sdx);
        SSY = SSY*ER;
        SM  = MN;
    }

    // butterfly merge across the 16 n-lanes
    #pragma unroll
    for (int off = 1; off < 16; off <<= 1) {
        f32x4 M2, L2, X2, Y2;
        #pragma unroll
        for (int k = 0; k < 4; ++k) {
            M2[k] = __shfl_xor(SM[k],  off);
            L2[k] = __shfl_xor(SL[k],  off);
            X2[k] = __shfl_xor(SSX[k], off);
            Y2[k] = __shfl_xor(SSY[k], off);
        }
        f32x4 MN = vmax4(SM, M2);
        f32x4 EA = vexp4(SM - MN);
        f32x4 EB = vexp4(M2 - MN);
        SL  = SL *EA + L2*EB;
        SSX = SSX*EA + X2*EB;
        SSY = SSY*EA + Y2*EB;
        SM  = MN;
    }

    if (n == 0) {
        #pragma unroll
        for (int r = 0; r < 4; ++r) {
            int w = wt*16 + m0 + r;
            int pix = (b*HH + h)*WW + w;
            float* p = &part[(size_t)(g*NPIX + pix)*4];
            p[0] = SM[r]; p[1] = SL[r]; p[2] = SSX[r]; p[3] = SSY[r];
        }
    }
}

// ---- merge the 3 dx-group partials (scaled domain), emit flow ----
__global__ __launch_bounds__(256) void merge_kernel(const float* __restrict__ part,
                                                    float* __restrict__ out) {
    int idx = blockIdx.x*256 + threadIdx.x;
    if (idx >= NPIX) return;
    const float* p0 = &part[(size_t)idx*4];
    const float* p1 = &part[(size_t)(NPIX + idx)*4];
    const float* p2 = &part[(size_t)(2*NPIX + idx)*4];
    float M = fmax_f(fmax_f(p0[0], p1[0]), p2[0]);
    float e0 = __builtin_amdgcn_exp2f(p0[0] - M);
    float e1 = __builtin_amdgcn_exp2f(p1[0] - M);
    float e2 = __builtin_amdgcn_exp2f(p2[0] - M);
    float L  = p0[1]*e0 + p1[1]*e1 + p2[1]*e2;
    float SX = p0[2]*e0 + p1[2]*e1 + p2[2]*e2;
    float SY = p0[3]*e0 + p1[3]*e1 + p2[3]*e2;
    int b = idx / (HH*WW), rem = idx % (HH*WW);
    out[(b*2 + 0)*(HH*WW) + rem] = SX / L;
    out[(b*2 + 1)*(HH*WW) + rem] = SY / L;
}

extern "C" void kernel_launch(void* const* d_in, const int* in_sizes, int n_in,
                              void* d_out, int out_size, void* d_ws, size_t ws_size,
                              hipStream_t stream) {
    const float* in1 = (const float*)d_in[0];
    const float* in2 = (const float*)d_in[1];
    float* out = (float*)d_out;
    unsigned short* in2s = (unsigned short*)d_ws;
    float* part = (float*)((char*)d_ws + IN2S_BYTES);   // [3][NPIX][4]

    pack_kernel <<<1120, 256, 0, stream>>>(in2, in2s);
    corr_kernel <<<1344, 448, 0, stream>>>(in1, in2s, part);
    merge_kernel<<<(NPIX+255)/256, 256, 0, stream>>>(part, out);
}